// Round 9
// baseline (557.042 us; speedup 1.0000x reference)
//
#include <hip/hip_runtime.h>

// 2-layer LSTM (H=50, B=4096, T=512, D_in=1) + FC(50->1), fused MFMA, round 9.
//
// Structure from r8 (13 waves x 1 tile, BT=16, 1 block/CU, 1 barrier/iter,
// gate-permuted rows, f16 2-product weights, single-f16 h state).
// KEY CHANGE: DEPTH-2 SOFTWARE PIPELINE.
//   iter i computes L0(t=i) and L1(t=i-2).
//   L1's h1-operand h1(i-2) = the b0/b1 fragments read at iter i-1 -> kept in
//   REGISTERS across the barrier. Post-barrier, L1's first 4 MFMAs issue with
//   ZERO memory wait (r8: every wave stalled ~150cyc on ds_read before any
//   MFMA). h2(i-3) read from buf P as before. Reads stay 4 b128/wave-iter.
//   Parity check (2 buffers still suffice): h1(g) lives in buf (g&1)^... all
//   producer->consumer pairs separated by >=1 barrier; h2 slot in buf P holds
//   gens i-3, i-1 (2-iter cycle), read-then-overwrite split by the barrier.
//   Also: L1 acc split into 2 parallel 4-chains (reg-half || LDS-half) + 4
//   adds; L0 split 2+2 -> accumulator dependency latency halved.
// B-frag layout (r2-r8-verified): k -> ks=k>>5, lane=((k>>3)&3)*16+n, j=k&7.
// Numerics identical to r8 (passed, absmax 0.00195): add-order change ~2^-24.

#define TT 512
#define HH 50
#define BT 16
#define NTHR 832   // 13 waves
#define L2E 1.44269504f

typedef _Float16 half8 __attribute__((ext_vector_type(8)));
typedef float floatx4 __attribute__((ext_vector_type(4)));

static __device__ __forceinline__ float fexp2(float x) { return __builtin_amdgcn_exp2f(x); }
static __device__ __forceinline__ float frcp(float x)  { return __builtin_amdgcn_rcpf(x); }

// fused LSTM cell: c' = sig(gf)*c + sig(gi)*tanh(gg); returns h = sig(go)*tanh(c').
// 5 exp + 3 rcp; c clamped before the tanh-exp so rcp(inf) can't NaN.
static __device__ __forceinline__ float cell_update(float gi, float gf, float gg,
                                                    float go, float& c) {
    float Ei  = fexp2(gi * -L2E);
    float Eg  = fexp2(gg * (-2.0f * L2E));
    float Ef  = fexp2(gf * -L2E);
    float Rig = frcp((1.0f + Ei) * (1.0f + Eg));
    float Rf  = frcp(1.0f + Ef);
    c = c * Rf + (1.0f - Eg) * Rig;
    float cl = fminf(fmaxf(c, -18.0f), 18.0f);
    float Eo = fexp2(go * -L2E);
    float Ec = fexp2(cl * (-2.0f * L2E));
    float R  = frcp((1.0f + Eo) * (1.0f + Ec));
    return (1.0f - Ec) * R;
}

#define MFMA(a, b, c) __builtin_amdgcn_mfma_f32_16x16x32_f16((a), (b), (c), 0, 0, 0)

__global__ __launch_bounds__(NTHR, 4) void lstm_mfma(
    const float* __restrict__ x,
    const float* __restrict__ W_ih0, const float* __restrict__ W_hh0,
    const float* __restrict__ b_ih0, const float* __restrict__ b_hh0,
    const float* __restrict__ W_ih1, const float* __restrict__ W_hh1,
    const float* __restrict__ b_ih1, const float* __restrict__ b_hh1,
    const float* __restrict__ W_fc,  const float* __restrict__ b_fc,
    float* __restrict__ out)
{
    __shared__ __align__(16) _Float16 Hf[2][2048];   // [buf][(ks*64+lane)*8+j]
    __shared__ float xs[TT * BT];

    const int tid = threadIdx.x;
    const int ln  = tid & 63;
    const int wv  = tid >> 6;         // wave 0..12 == tile index (both layers)
    const int m   = ln & 15;          // batch col
    const int q   = ln >> 4;          // quad
    const int b0g = blockIdx.x * BT;

    // ---------------- one-time init ----------------
    for (int i = tid; i < BT * TT; i += NTHR) {
        int b = i & 15, t = i >> 4;
        xs[t * BT + b] = x[(size_t)(b0g + b) * TT + t];
    }
    for (int i = tid; i < 2 * 2048; i += NTHR) ((_Float16*)Hf)[i] = (_Float16)0.f;

    // ---- A-fragments (gate-permuted rows), f16 hi/lo ----
    const int  uA   = 4 * wv + (m >> 2);
    const int  gA   = m & 3;
    const bool rokA = (uA < HH);
    const int  wrow = gA * HH + uA;

    half8 a0h[2], a0l[2];             // layer-0 (W_hh0), ks 0..1
    half8 a1h[4], a1l[4];             // layer-1 ([W_ih1|pad|W_hh1|pad]), ks 0..3
#pragma unroll
    for (int ks = 0; ks < 2; ++ks) {
        half8 h8, l8;
#pragma unroll
        for (int j = 0; j < 8; ++j) {
            int k = ks * 32 + q * 8 + j;
            float w = (rokA && k < HH) ? W_hh0[wrow * HH + k] : 0.f;
            _Float16 wh = (_Float16)w;
            _Float16 wl = (_Float16)(w - (float)wh);
            h8[j] = wh; l8[j] = wl;
        }
        a0h[ks] = h8; a0l[ks] = l8;
    }
#pragma unroll
    for (int ks = 0; ks < 4; ++ks) {
        half8 h8, l8;
#pragma unroll
        for (int j = 0; j < 8; ++j) {
            int k = ks * 32 + q * 8 + j;
            float w = 0.f;
            if (rokA) {
                if (k < HH)                      w = W_ih1[wrow * HH + k];
                else if (k >= 64 && k < 64 + HH) w = W_hh1[wrow * HH + (k - 64)];
            }
            _Float16 wh = (_Float16)w;
            _Float16 wl = (_Float16)(w - (float)wh);
            h8[j] = wh; l8[j] = wl;
        }
        a1h[ks] = h8; a1l[ks] = l8;
    }

    // ---- C-lane constants: unit uC = 4*wv + q, batch m, gate g = reg ----
    const int  uC = 4 * wv + q;       // 50,51 (wave 12, q>=2): dummies -> zero-wt K slots
    const bool vC = (uC < HH);
    float cc0[4], bw0[4], cc1[4];
#pragma unroll
    for (int g = 0; g < 4; ++g) {
        int rg = g * HH + (vC ? uC : 0);
        cc0[g] = vC ? (b_ih0[rg] + b_hh0[rg]) : 0.f;
        bw0[g] = vC ? W_ih0[rg] : 0.f;
        cc1[g] = vC ? (b_ih1[rg] + b_hh1[rg]) : 0.f;
    }
    const int kh = uC & 63;           // dummy units 50/51 -> zero-weight K slots
    const int widx = ((kh >> 5) * 64 + ((kh >> 3) & 3) * 16 + m) * 8 + (kh & 7);
    float c1 = 0.f, c2 = 0.f;

    // carry registers: previous iteration's b0,b1 = h1(i-2) for L1's reg-half
    half8 ph0 = (half8)(_Float16)0.f, ph1 = (half8)(_Float16)0.f;

    __syncthreads();

    // iter i (P = i&1, compile-time):
    //   reads  : b0,b1 = h1(i-1) [buf P]  (feed L0 now, become ph for next iter)
    //            b2,b3 = h2(i-3) [buf P]  (feed L1's LDS-half)
    //   L1(i-2): accR chain on ph0/ph1 (REGISTERS, zero wait)  ||  accM chain on
    //            b2,b3; merge; update c2 -> h2(i-2) -> buf P^1
    //   L0(i)  : split 2+2 chains on b0,b1; update c1 -> h1(i) -> buf P^1
#define ITER(ttv, P, DO_L0, DO_L1)                                        \
    {                                                                     \
        half8 b0 = *(const half8*)&Hf[(P)][(0 * 64 + ln) * 8];            \
        half8 b1 = *(const half8*)&Hf[(P)][(1 * 64 + ln) * 8];            \
        half8 b2 = *(const half8*)&Hf[(P)][(2 * 64 + ln) * 8];            \
        half8 b3 = *(const half8*)&Hf[(P)][(3 * 64 + ln) * 8];            \
        if (DO_L1) {                                                      \
            floatx4 accR, accM;                                           \
            _Pragma("unroll")                                             \
            for (int g = 0; g < 4; ++g) { accR[g] = cc1[g]; accM[g] = 0.f; } \
            accR = MFMA(a1h[0], ph0, accR);                               \
            accR = MFMA(a1l[0], ph0, accR);                               \
            accR = MFMA(a1h[1], ph1, accR);                               \
            accR = MFMA(a1l[1], ph1, accR);                               \
            accM = MFMA(a1h[2], b2, accM);                                \
            accM = MFMA(a1l[2], b2, accM);                                \
            accM = MFMA(a1h[3], b3, accM);                                \
            accM = MFMA(a1l[3], b3, accM);                                \
            float h = cell_update(accR[0] + accM[0], accR[1] + accM[1],   \
                                  accR[2] + accM[2], accR[3] + accM[3], c2); \
            Hf[(P) ^ 1][widx + 1024] = (_Float16)h;                       \
        }                                                                 \
        if (DO_L0) {                                                      \
            const float xv = xs[(ttv) * BT + m];                          \
            floatx4 accA, accB;                                           \
            _Pragma("unroll")                                             \
            for (int g = 0; g < 4; ++g) { accA[g] = cc0[g] + bw0[g] * xv; accB[g] = 0.f; } \
            accA = MFMA(a0h[0], b0, accA);                                \
            accA = MFMA(a0l[0], b0, accA);                                \
            accB = MFMA(a0h[1], b1, accB);                                \
            accB = MFMA(a0l[1], b1, accB);                                \
            float h = cell_update(accA[0] + accB[0], accA[1] + accB[1],   \
                                  accA[2] + accB[2], accA[3] + accB[3], c1); \
            Hf[(P) ^ 1][widx] = (_Float16)h;                              \
        }                                                                 \
        ph0 = b0; ph1 = b1;                                               \
        __syncthreads();                                                  \
    }

    // ---- pipeline fill: i = 0,1 (L1 disabled) ----
    ITER(0, 0, true, false);
    ITER(1, 1, true, false);
    // ---- steady state: i = 2..511 as compile-time-parity pairs ----
    for (int k = 1; k <= 255; ++k) {
        ITER(2 * k,     0, true, true);
        ITER(2 * k + 1, 1, true, true);
    }
    // ---- pipeline drain: i = 512, 513 (L0 disabled) ----
    ITER(512, 0, false, true);
    ITER(513, 1, false, true);

    // ---- FC epilogue: h2(511) written at iter 513 -> buf (513&1)^1 = 0 ----
    if (tid < BT) {
        float a = b_fc[0];
        for (int u = 0; u < HH; ++u) {
            int k = 64 + u;
            int idx = ((k >> 5) * 64 + ((k >> 3) & 3) * 16 + tid) * 8 + (k & 7);
            a = fmaf((float)Hf[0][idx], W_fc[u], a);
        }
        out[b0g + tid] = a;
    }
#undef ITER
}

extern "C" void kernel_launch(void* const* d_in, const int* in_sizes, int n_in,
                              void* d_out, int out_size, void* d_ws, size_t ws_size,
                              hipStream_t stream) {
    const float* x     = (const float*)d_in[0];
    const float* W_ih0 = (const float*)d_in[1];
    const float* W_hh0 = (const float*)d_in[2];
    const float* b_ih0 = (const float*)d_in[3];
    const float* b_hh0 = (const float*)d_in[4];
    const float* W_ih1 = (const float*)d_in[5];
    const float* W_hh1 = (const float*)d_in[6];
    const float* b_ih1 = (const float*)d_in[7];
    const float* b_hh1 = (const float*)d_in[8];
    const float* W_fc  = (const float*)d_in[9];
    const float* b_fc  = (const float*)d_in[10];
    float* out = (float*)d_out;

    dim3 grid(4096 / BT);   // 256 blocks = 1/CU
    dim3 block(NTHR);       // 13 waves
    lstm_mfma<<<grid, block, 0, stream>>>(x, W_ih0, W_hh0, b_ih0, b_hh0,
                                          W_ih1, W_hh1, b_ih1, b_hh1,
                                          W_fc, b_fc, out);
}

// Round 11
// 532.429 us; speedup vs baseline: 1.0462x; 1.0462x over previous
//
#include <hip/hip_runtime.h>

// 2-layer LSTM (H=50, B=4096, T=512, D_in=1) + FC(50->1), fused MFMA, round 11.
//
// = round 10 (producer/consumer wave groups, no block barrier in the time loop)
// with the SYNC COUNTER FIX: arrive() runs on all 64 lanes -> +64 per wave
// (m20: compiler coalesces to one add of active-lane count). r10's targets
// assumed +1/wave, so every gate opened ~64x early -> racy stale reads
// (absmax 5.6e-2). All targets now scaled by AR=64.
//
//   waves 0-5  (L0): tiles {w, w+6} (+12 for wave 5). Exchange h1 per step.
//   waves 6-12 (L1): tiles {w', w'+7} (13=dummy).     Exchange h2 per step.
// L1 never feeds L0 -> L1 trails L0 by 1..4 steps, consuming h1 from a 4-deep
// ring. Sync: monotonic LDS counters, release ds_add / acquire spin + s_sleep.
//   L0 step t: [t>=4] wait ctrB>=AR*7*(t-3)  (ring WAR: L1 done step t-4)
//              read h1(t-1), compute, write h1(t) -> slot t&3,
//              arrive ctrA; wait ctrA>=AR*6*(t+1)   (L0 group barrier)
//   L1 step u: wait ctrA>=AR*6*(u+1)               (h1(u) ready)
//              read h1(u) + h2(u-1), compute, write h2(u),
//              arrive ctrB; wait ctrB>=AR*7*(u+1)   (L1 group barrier)
// f16 2-product weights (hi+lo), single-f16 h state (r8 numerics, passed).
// B-frag layout (r2-r9-verified): k -> ks=k>>5, lane=((k>>3)&3)*16+n, j=k&7.

#define TT  512
#define HH  50
#define BT  16
#define NTHR 832
#define NL0 6
#define NL1 7
#define AR  64      // counter increments per wave-arrive (64 lanes)
#define L2E 1.44269504f

typedef _Float16 half8 __attribute__((ext_vector_type(8)));
typedef float floatx4 __attribute__((ext_vector_type(4)));

static __device__ __forceinline__ float fexp2(float x) { return __builtin_amdgcn_exp2f(x); }
static __device__ __forceinline__ float frcp(float x)  { return __builtin_amdgcn_rcpf(x); }

static __device__ __forceinline__ float cell_update(float gi, float gf, float gg,
                                                    float go, float& c) {
    float Ei  = fexp2(gi * -L2E);
    float Eg  = fexp2(gg * (-2.0f * L2E));
    float Ef  = fexp2(gf * -L2E);
    float Rig = frcp((1.0f + Ei) * (1.0f + Eg));
    float Rf  = frcp(1.0f + Ef);
    c = c * Rf + (1.0f - Eg) * Rig;
    float cl = fminf(fmaxf(c, -18.0f), 18.0f);
    float Eo = fexp2(go * -L2E);
    float Ec = fexp2(cl * (-2.0f * L2E));
    float R  = frcp((1.0f + Eo) * (1.0f + Ec));
    return (1.0f - Ec) * R;
}

static __device__ __forceinline__ void wait_ge(unsigned* ctr, unsigned tgt) {
    unsigned guard = 0;
    while (__hip_atomic_load(ctr, __ATOMIC_ACQUIRE, __HIP_MEMORY_SCOPE_WORKGROUP) < tgt) {
        __builtin_amdgcn_s_sleep(1);
        if (++guard > (1u << 22)) break;   // anti-hang escape (bug -> wrong answer)
    }
}
static __device__ __forceinline__ void arrive(unsigned* ctr) {
    __threadfence_block();                 // drain prior LDS writes
    __hip_atomic_fetch_add(ctr, 1u, __ATOMIC_RELEASE, __HIP_MEMORY_SCOPE_WORKGROUP);
}   // executed by all 64 lanes at full exec -> +AR per wave

#define MFMA(a, b, c) __builtin_amdgcn_mfma_f32_16x16x32_f16((a), (b), (c), 0, 0, 0)

__global__ __launch_bounds__(NTHR) void lstm_mfma(
    const float* __restrict__ x,
    const float* __restrict__ W_ih0, const float* __restrict__ W_hh0,
    const float* __restrict__ b_ih0, const float* __restrict__ b_hh0,
    const float* __restrict__ W_ih1, const float* __restrict__ W_hh1,
    const float* __restrict__ b_ih1, const float* __restrict__ b_hh1,
    const float* __restrict__ W_fc,  const float* __restrict__ b_fc,
    float* __restrict__ out)
{
    __shared__ __align__(16) _Float16 h1ring[4][1024];  // gen: (ks*64+lane)*8+j, ks=0..1
    __shared__ __align__(16) _Float16 h2buf[2][1024];   // gen: local ks 0..1 (= k-64)
    __shared__ float xs[TT * BT];
    __shared__ unsigned ctrA, ctrB;

    const int tid = threadIdx.x;
    const int ln  = tid & 63;
    const int wv  = tid >> 6;
    const int m   = ln & 15;
    const int q   = ln >> 4;
    const int b0g = blockIdx.x * BT;

    // ---------------- one-time init ----------------
    for (int i = tid; i < BT * TT; i += NTHR) {
        int b = i & 15, t = i >> 4;
        xs[t * BT + b] = x[(size_t)(b0g + b) * TT + t];
    }
    for (int i = tid; i < 4 * 1024; i += NTHR) ((_Float16*)h1ring)[i] = (_Float16)0.f;
    for (int i = tid; i < 2 * 1024; i += NTHR) ((_Float16*)h2buf)[i]  = (_Float16)0.f;
    if (tid == 0) { ctrA = 0u; ctrB = 0u; }
    __syncthreads();

    if (wv < NL0) {
        // ================= L0 group: waves 0..5 =================
        const int t0 = wv, t1 = wv + 6, t2 = 12;
        const bool has3 = (wv == 5);
        int tiles[3] = { t0, t1, t2 };

        half8 ah[3][2], al[3][2];
        float cc0[3][4], bw0[3][4];
        int   widx[3];
#pragma unroll
        for (int s = 0; s < 3; ++s) {
            const int uA = 4 * tiles[s] + (m >> 2);
            const int gA = m & 3;
            const bool rokA = (uA < HH);
            const int wrow = gA * HH + (rokA ? uA : 0);
#pragma unroll
            for (int ks = 0; ks < 2; ++ks) {
                half8 h8, l8;
#pragma unroll
                for (int j = 0; j < 8; ++j) {
                    int k = ks * 32 + q * 8 + j;
                    float w = (rokA && k < HH) ? W_hh0[wrow * HH + k] : 0.f;
                    _Float16 wh = (_Float16)w;
                    h8[j] = wh; l8[j] = (_Float16)(w - (float)wh);
                }
                ah[s][ks] = h8; al[s][ks] = l8;
            }
            const int uC = 4 * tiles[s] + q;
            const bool vC = (uC < HH);
#pragma unroll
            for (int g = 0; g < 4; ++g) {
                int rg = g * HH + (vC ? uC : 0);
                cc0[s][g] = vC ? (b_ih0[rg] + b_hh0[rg]) : 0.f;
                bw0[s][g] = vC ? W_ih0[rg] : 0.f;
            }
            widx[s] = ((uC >> 5) * 64 + ((uC >> 3) & 3) * 16 + m) * 8 + (uC & 7);
        }
        float c1[3] = {0.f, 0.f, 0.f};

        unsigned tgtB = AR * NL1;                 // AR*7*(t-3) at t=4
        unsigned tgtA = AR * NL0;                 // AR*6*(t+1) at t=0
        for (int t = 0; t < TT; ++t) {
            if (t >= 4) { wait_ge(&ctrB, tgtB); tgtB += AR * NL1; }
            const _Float16* rb = h1ring[(t + 3) & 3];   // h1(t-1); t=0 -> zeros
            half8 b0 = *(const half8*)&rb[(0 * 64 + ln) * 8];
            half8 b1 = *(const half8*)&rb[(1 * 64 + ln) * 8];
            const float xv = xs[t * BT + m];
            _Float16* wb = h1ring[t & 3];

            floatx4 acc[3];
#pragma unroll
            for (int s = 0; s < 3; ++s)
#pragma unroll
                for (int g = 0; g < 4; ++g) acc[s][g] = cc0[s][g] + bw0[s][g] * xv;
#pragma unroll
            for (int s = 0; s < 2; ++s) {
                acc[s] = MFMA(ah[s][0], b0, acc[s]);
                acc[s] = MFMA(al[s][0], b0, acc[s]);
                acc[s] = MFMA(ah[s][1], b1, acc[s]);
                acc[s] = MFMA(al[s][1], b1, acc[s]);
            }
            if (has3) {
                acc[2] = MFMA(ah[2][0], b0, acc[2]);
                acc[2] = MFMA(al[2][0], b0, acc[2]);
                acc[2] = MFMA(ah[2][1], b1, acc[2]);
                acc[2] = MFMA(al[2][1], b1, acc[2]);
            }
#pragma unroll
            for (int s = 0; s < 2; ++s) {
                float h = cell_update(acc[s][0], acc[s][1], acc[s][2], acc[s][3], c1[s]);
                wb[widx[s]] = (_Float16)h;
            }
            if (has3) {
                float h = cell_update(acc[2][0], acc[2][1], acc[2][2], acc[2][3], c1[2]);
                wb[widx[2]] = (_Float16)h;
            }
            arrive(&ctrA);
            wait_ge(&ctrA, tgtA); tgtA += AR * NL0;
        }
    } else {
        // ================= L1 group: waves 6..12 =================
        const int w7 = wv - NL0;                  // 0..6
        const int t0 = w7, t1 = w7 + 7;           // t1==13 -> dummy (w7==6)
        const bool has2 = (w7 != 6);
        int tiles[2] = { t0, t1 };

        half8 ah[2][4], al[2][4];
        float cc1[2][4];
        int   widx[2];
#pragma unroll
        for (int s = 0; s < 2; ++s) {
            const int uA = 4 * tiles[s] + (m >> 2);
            const int gA = m & 3;
            const bool rokA = (uA < HH);
            const int wrow = gA * HH + (rokA ? uA : 0);
#pragma unroll
            for (int ks = 0; ks < 4; ++ks) {
                half8 h8, l8;
#pragma unroll
                for (int j = 0; j < 8; ++j) {
                    int k = ks * 32 + q * 8 + j;
                    float w = 0.f;
                    if (rokA) {
                        if (k < HH)                      w = W_ih1[wrow * HH + k];
                        else if (k >= 64 && k < 64 + HH) w = W_hh1[wrow * HH + (k - 64)];
                    }
                    _Float16 wh = (_Float16)w;
                    h8[j] = wh; l8[j] = (_Float16)(w - (float)wh);
                }
                ah[s][ks] = h8; al[s][ks] = l8;
            }
            const int uC = 4 * tiles[s] + q;
            const bool vC = (uC < HH);
#pragma unroll
            for (int g = 0; g < 4; ++g) {
                int rg = g * HH + (vC ? uC : 0);
                cc1[s][g] = vC ? (b_ih1[rg] + b_hh1[rg]) : 0.f;
            }
            const int kh = uC & 63;
            widx[s] = ((kh >> 5) * 64 + ((kh >> 3) & 3) * 16 + m) * 8 + (kh & 7);
        }
        float c2[2] = {0.f, 0.f};

        unsigned tgtA = AR * NL0;                 // AR*6*(u+1)
        unsigned tgtB = AR * NL1;                 // AR*7*(u+1)
        for (int u = 0; u < TT; ++u) {
            wait_ge(&ctrA, tgtA); tgtA += AR * NL0;    // h1(u) ready
            const _Float16* rb = h1ring[u & 3];
            half8 b0 = *(const half8*)&rb[(0 * 64 + ln) * 8];
            half8 b1 = *(const half8*)&rb[(1 * 64 + ln) * 8];
            const _Float16* rb2 = h2buf[(u + 1) & 1];  // h2(u-1); u=0 -> zeros
            half8 b2 = *(const half8*)&rb2[(0 * 64 + ln) * 8];
            half8 b3 = *(const half8*)&rb2[(1 * 64 + ln) * 8];
            _Float16* wb = h2buf[u & 1];

            floatx4 acc[2];
#pragma unroll
            for (int s = 0; s < 2; ++s)
#pragma unroll
                for (int g = 0; g < 4; ++g) acc[s][g] = cc1[s][g];
            {
                acc[0] = MFMA(ah[0][0], b0, acc[0]);
                acc[0] = MFMA(al[0][0], b0, acc[0]);
                acc[0] = MFMA(ah[0][1], b1, acc[0]);
                acc[0] = MFMA(al[0][1], b1, acc[0]);
                acc[0] = MFMA(ah[0][2], b2, acc[0]);
                acc[0] = MFMA(al[0][2], b2, acc[0]);
                acc[0] = MFMA(ah[0][3], b3, acc[0]);
                acc[0] = MFMA(al[0][3], b3, acc[0]);
            }
            if (has2) {
                acc[1] = MFMA(ah[1][0], b0, acc[1]);
                acc[1] = MFMA(al[1][0], b0, acc[1]);
                acc[1] = MFMA(ah[1][1], b1, acc[1]);
                acc[1] = MFMA(al[1][1], b1, acc[1]);
                acc[1] = MFMA(ah[1][2], b2, acc[1]);
                acc[1] = MFMA(al[1][2], b2, acc[1]);
                acc[1] = MFMA(ah[1][3], b3, acc[1]);
                acc[1] = MFMA(al[1][3], b3, acc[1]);
            }
            {
                float h = cell_update(acc[0][0], acc[0][1], acc[0][2], acc[0][3], c2[0]);
                wb[widx[0]] = (_Float16)h;
            }
            if (has2) {
                float h = cell_update(acc[1][0], acc[1][1], acc[1][2], acc[1][3], c2[1]);
                wb[widx[1]] = (_Float16)h;
            }
            arrive(&ctrB);
            wait_ge(&ctrB, tgtB); tgtB += AR * NL1;
        }
    }

    __syncthreads();

    // ---------------- FC epilogue: h2(511) in h2buf[511&1 = 1] ----------------
    if (tid < BT) {
        float a = b_fc[0];
        for (int u = 0; u < HH; ++u) {
            int idx = ((u >> 5) * 64 + ((u >> 3) & 3) * 16 + tid) * 8 + (u & 7);
            a = fmaf((float)h2buf[1][idx], W_fc[u], a);
        }
        out[b0g + tid] = a;
    }
}

extern "C" void kernel_launch(void* const* d_in, const int* in_sizes, int n_in,
                              void* d_out, int out_size, void* d_ws, size_t ws_size,
                              hipStream_t stream) {
    const float* x     = (const float*)d_in[0];
    const float* W_ih0 = (const float*)d_in[1];
    const float* W_hh0 = (const float*)d_in[2];
    const float* b_ih0 = (const float*)d_in[3];
    const float* b_hh0 = (const float*)d_in[4];
    const float* W_ih1 = (const float*)d_in[5];
    const float* W_hh1 = (const float*)d_in[6];
    const float* b_ih1 = (const float*)d_in[7];
    const float* b_hh1 = (const float*)d_in[8];
    const float* W_fc  = (const float*)d_in[9];
    const float* b_fc  = (const float*)d_in[10];
    float* out = (float*)d_out;

    dim3 grid(4096 / BT);   // 256 blocks = 1/CU
    dim3 block(NTHR);       // 13 waves: 6 L0 + 7 L1, counter-synced
    lstm_mfma<<<grid, block, 0, stream>>>(x, W_ih0, W_hh0, b_ih0, b_hh0,
                                          W_ih1, W_hh1, b_ih1, b_hh1,
                                          W_fc, b_fc, out);
}

// Round 12
// 522.065 us; speedup vs baseline: 1.0670x; 1.0199x over previous
//
#include <hip/hip_runtime.h>

// 2-layer LSTM (H=50, B=4096, T=512, D_in=1) + FC(50->1), fused MFMA — FINAL.
// (= round-8 kernel, the empirical best at 523 us; rounds 9-11 scheduling
// variants were neutral or worse. See session journal for the plateau analysis:
// 512-step serial recurrence, per-step envelope ~2440 cyc = LDS all-to-all
// h-exchange + quarter-rate transcendental chain + barrier convoy; VALU issue
// model matches measured VALUBusy 48.8% exactly.)
//
// Structure: 256 blocks (1/CU) x 832 threads (13 waves), 16 batches/block,
// wave w owns M-tile w for BOTH layers (balanced: 12 MFMA + 2 updates each).
// mfma_f32_16x16x32_f16; weights as f16 hi+lo (2 products, weight err 2^-22);
// h state as single RN f16 (rel err 2^-11) -> 4 ds_read_b128/wave-iter.
// Gate-permuted A rows: packed row 4u+g -> lane (q,m) holds all 4 gates of
// unit 4*wv+q, batch m, in its 4 acc regs -> in-register cell update, h
// written straight to B-frag LDS (2-byte store). Double-buffered on parity;
// ONE __syncthreads per iteration; iter tt computes L0(t=tt), L1(t=tt-1).
// B-frag layout: k -> ks=k>>5, lane=((k>>3)&3)*16+n, j=k&7 (r2-r8 verified).

#define TT 512
#define HH 50
#define BT 16
#define NTHR 832   // 13 waves
#define L2E 1.44269504f

typedef _Float16 half8 __attribute__((ext_vector_type(8)));
typedef float floatx4 __attribute__((ext_vector_type(4)));

static __device__ __forceinline__ float fexp2(float x) { return __builtin_amdgcn_exp2f(x); }
static __device__ __forceinline__ float frcp(float x)  { return __builtin_amdgcn_rcpf(x); }

// fused LSTM cell: c' = sig(gf)*c + sig(gi)*tanh(gg); returns h = sig(go)*tanh(c').
// 5 exp + 3 rcp; c clamped before the tanh-exp so rcp(inf) can't NaN.
static __device__ __forceinline__ float cell_update(float gi, float gf, float gg,
                                                    float go, float& c) {
    float Ei  = fexp2(gi * -L2E);
    float Eg  = fexp2(gg * (-2.0f * L2E));
    float Ef  = fexp2(gf * -L2E);
    float Rig = frcp((1.0f + Ei) * (1.0f + Eg));
    float Rf  = frcp(1.0f + Ef);
    c = c * Rf + (1.0f - Eg) * Rig;
    float cl = fminf(fmaxf(c, -18.0f), 18.0f);
    float Eo = fexp2(go * -L2E);
    float Ec = fexp2(cl * (-2.0f * L2E));
    float R  = frcp((1.0f + Eo) * (1.0f + Ec));
    return (1.0f - Ec) * R;
}

#define MFMA(a, b, c) __builtin_amdgcn_mfma_f32_16x16x32_f16((a), (b), (c), 0, 0, 0)

__global__ __launch_bounds__(NTHR, 4) void lstm_mfma(
    const float* __restrict__ x,
    const float* __restrict__ W_ih0, const float* __restrict__ W_hh0,
    const float* __restrict__ b_ih0, const float* __restrict__ b_hh0,
    const float* __restrict__ W_ih1, const float* __restrict__ W_hh1,
    const float* __restrict__ b_ih1, const float* __restrict__ b_hh1,
    const float* __restrict__ W_fc,  const float* __restrict__ b_fc,
    float* __restrict__ out)
{
    __shared__ __align__(16) _Float16 Hf[2][2048];   // [buf][(ks*64+lane)*8+j]
    __shared__ float xs[TT * BT];

    const int tid = threadIdx.x;
    const int ln  = tid & 63;
    const int wv  = tid >> 6;         // wave 0..12 == tile index (both layers)
    const int m   = ln & 15;          // batch col
    const int q   = ln >> 4;          // quad
    const int b0g = blockIdx.x * BT;

    // ---------------- one-time init ----------------
    for (int i = tid; i < BT * TT; i += NTHR) {
        int b = i & 15, t = i >> 4;
        xs[t * BT + b] = x[(size_t)(b0g + b) * TT + t];
    }
    for (int i = tid; i < 2 * 2048; i += NTHR) ((_Float16*)Hf)[i] = (_Float16)0.f;

    // ---- A-fragments (gate-permuted rows), f16 hi/lo ----
    const int  uA   = 4 * wv + (m >> 2);
    const int  gA   = m & 3;
    const bool rokA = (uA < HH);
    const int  wrow = gA * HH + uA;

    half8 a0h[2], a0l[2];             // layer-0 (W_hh0), ks 0..1
    half8 a1h[4], a1l[4];             // layer-1 ([W_ih1|pad|W_hh1|pad]), ks 0..3
#pragma unroll
    for (int ks = 0; ks < 2; ++ks) {
        half8 h8, l8;
#pragma unroll
        for (int j = 0; j < 8; ++j) {
            int k = ks * 32 + q * 8 + j;
            float w = (rokA && k < HH) ? W_hh0[wrow * HH + k] : 0.f;
            _Float16 wh = (_Float16)w;
            _Float16 wl = (_Float16)(w - (float)wh);
            h8[j] = wh; l8[j] = wl;
        }
        a0h[ks] = h8; a0l[ks] = l8;
    }
#pragma unroll
    for (int ks = 0; ks < 4; ++ks) {
        half8 h8, l8;
#pragma unroll
        for (int j = 0; j < 8; ++j) {
            int k = ks * 32 + q * 8 + j;
            float w = 0.f;
            if (rokA) {
                if (k < HH)                      w = W_ih1[wrow * HH + k];
                else if (k >= 64 && k < 64 + HH) w = W_hh1[wrow * HH + (k - 64)];
            }
            _Float16 wh = (_Float16)w;
            _Float16 wl = (_Float16)(w - (float)wh);
            h8[j] = wh; l8[j] = wl;
        }
        a1h[ks] = h8; a1l[ks] = l8;
    }

    // ---- C-lane constants: unit uC = 4*wv + q, batch m, gate g = reg ----
    const int  uC = 4 * wv + q;       // 50,51 (wave 12, q>=2): dummies -> zero-wt K slots
    const bool vC = (uC < HH);
    float cc0[4], bw0[4], cc1[4];
#pragma unroll
    for (int g = 0; g < 4; ++g) {
        int rg = g * HH + (vC ? uC : 0);
        cc0[g] = vC ? (b_ih0[rg] + b_hh0[rg]) : 0.f;
        bw0[g] = vC ? W_ih0[rg] : 0.f;
        cc1[g] = vC ? (b_ih1[rg] + b_hh1[rg]) : 0.f;
    }
    const int kh = uC & 63;           // dummy units 50/51 land in zero-weight K slots
    const int widx = ((kh >> 5) * 64 + ((kh >> 3) & 3) * 16 + m) * 8 + (kh & 7);
    float c1 = 0.f, c2 = 0.f;

    __syncthreads();

    // one iteration: snapshot buf P (compile-time), L0(t=ttv) if DO_L0,
    // L1(t=ttv-1), write h -> buf P^1, barrier.
#define ITER(ttv, P, DO_L0)                                               \
    {                                                                     \
        half8 b0 = *(const half8*)&Hf[(P)][(0 * 64 + ln) * 8];            \
        half8 b1 = *(const half8*)&Hf[(P)][(1 * 64 + ln) * 8];            \
        half8 b2 = *(const half8*)&Hf[(P)][(2 * 64 + ln) * 8];            \
        half8 b3 = *(const half8*)&Hf[(P)][(3 * 64 + ln) * 8];            \
        if (DO_L0) {                                                      \
            const float xv = xs[(ttv) * BT + m];                          \
            floatx4 acc;                                                  \
            _Pragma("unroll")                                             \
            for (int g = 0; g < 4; ++g) acc[g] = cc0[g] + bw0[g] * xv;    \
            acc = MFMA(a0h[0], b0, acc);                                  \
            acc = MFMA(a0l[0], b0, acc);                                  \
            acc = MFMA(a0h[1], b1, acc);                                  \
            acc = MFMA(a0l[1], b1, acc);                                  \
            float h = cell_update(acc[0], acc[1], acc[2], acc[3], c1);    \
            Hf[(P) ^ 1][widx] = (_Float16)h;                              \
        }                                                                 \
        {                                                                 \
            floatx4 acc;                                                  \
            _Pragma("unroll")                                             \
            for (int g = 0; g < 4; ++g) acc[g] = cc1[g];                  \
            acc = MFMA(a1h[0], b0, acc);                                  \
            acc = MFMA(a1l[0], b0, acc);                                  \
            acc = MFMA(a1h[1], b1, acc);                                  \
            acc = MFMA(a1l[1], b1, acc);                                  \
            acc = MFMA(a1h[2], b2, acc);                                  \
            acc = MFMA(a1l[2], b2, acc);                                  \
            acc = MFMA(a1h[3], b3, acc);                                  \
            acc = MFMA(a1l[3], b3, acc);                                  \
            float h = cell_update(acc[0], acc[1], acc[2], acc[3], c2);    \
            Hf[(P) ^ 1][widx + 1024] = (_Float16)h;                       \
        }                                                                 \
        __syncthreads();                                                  \
    }

    // ---- tt = 0 (p=0): h=0 -> L0 needs no MFMA; h2(-1)=0 already in buf 1 ----
    {
        const float xv = xs[m];
        float h = cell_update(cc0[0] + bw0[0] * xv, cc0[1] + bw0[1] * xv,
                              cc0[2] + bw0[2] * xv, cc0[3] + bw0[3] * xv, c1);
        Hf[1][widx] = (_Float16)h;
        __syncthreads();
    }

    // ---- steady state: pairs (2k-1 [p=1], 2k [p=0]) for k = 1..255 ----
    for (int k = 1; k <= 255; ++k) {
        ITER(2 * k - 1, 1, true);
        ITER(2 * k,     0, true);
    }
    // ---- tail: tt = 511 (p=1, both), tt = 512 (p=0, L1 only) ----
    ITER(511, 1, true);
    ITER(512, 0, false);

    // ---------------- FC epilogue: h2(511) in buf 1, slots k = 64+u ----------------
    if (tid < BT) {
        float a = b_fc[0];
        for (int u = 0; u < HH; ++u) {
            int k = 64 + u;
            int idx = ((k >> 5) * 64 + ((k >> 3) & 3) * 16 + tid) * 8 + (k & 7);
            a = fmaf((float)Hf[1][idx], W_fc[u], a);
        }
        out[b0g + tid] = a;
    }
#undef ITER
}

extern "C" void kernel_launch(void* const* d_in, const int* in_sizes, int n_in,
                              void* d_out, int out_size, void* d_ws, size_t ws_size,
                              hipStream_t stream) {
    const float* x     = (const float*)d_in[0];
    const float* W_ih0 = (const float*)d_in[1];
    const float* W_hh0 = (const float*)d_in[2];
    const float* b_ih0 = (const float*)d_in[3];
    const float* b_hh0 = (const float*)d_in[4];
    const float* W_ih1 = (const float*)d_in[5];
    const float* W_hh1 = (const float*)d_in[6];
    const float* b_ih1 = (const float*)d_in[7];
    const float* b_hh1 = (const float*)d_in[8];
    const float* W_fc  = (const float*)d_in[9];
    const float* b_fc  = (const float*)d_in[10];
    float* out = (float*)d_out;

    dim3 grid(4096 / BT);   // 256 blocks = 1/CU
    dim3 block(NTHR);       // 13 waves
    lstm_mfma<<<grid, block, 0, stream>>>(x, W_ih0, W_hh0, b_ih0, b_hh0,
                                          W_ih1, W_hh1, b_ih1, b_hh1,
                                          W_fc, b_fc, out);
}

// Round 13
// 440.912 us; speedup vs baseline: 1.2634x; 1.1841x over previous
//
#include <hip/hip_runtime.h>

// 2-layer LSTM (H=50, B=4096, T=512, D_in=1) + FC(50->1), fused MFMA, round 13.
//
// = round-12 structure (13 waves x 1 tile, BT=16, 1 block/CU, 1 barrier/iter,
// gate-permuted rows, in-lane cell update, single-f16 h state) with two cuts:
//  1. SINGLE f16 WEIGHT PRODUCT (drop the lo-residual MFMA): 12 -> 6 MFMA per
//     wave-iter. Precision gamble, from the error budget: weight-quant noise
//     (2^-11, systematic) ~= h-quant noise (2^-11, random) ~3.5e-4/gate ->
//     expected absmax ~2x r12's 0.00195 ~= 0.004 < 0.0059 threshold.
//     If it fails, the session answer is the r12 kernel (locked, 522 us).
//  2. Merged-rcp cell update: c' = R*[c*(1+Ei)(1+Eg) + (1-Eg)(1+Ef)],
//     R = rcp((1+Ef)(1+Ei)(1+Eg)) -> 5 exp + 2 rcp (was 5+3).
// B-frag layout (r2-r12-verified): k -> ks=k>>5, lane=((k>>3)&3)*16+n, j=k&7.

#define TT 512
#define HH 50
#define BT 16
#define NTHR 832   // 13 waves
#define L2E 1.44269504f

typedef _Float16 half8 __attribute__((ext_vector_type(8)));
typedef float floatx4 __attribute__((ext_vector_type(4)));

static __device__ __forceinline__ float fexp2(float x) { return __builtin_amdgcn_exp2f(x); }
static __device__ __forceinline__ float frcp(float x)  { return __builtin_amdgcn_rcpf(x); }

// fused LSTM cell, merged-rcp form: 5 exp + 2 rcp.
// c' = sig(gf)*c + sig(gi)*tanh(gg)
//    = R * [ c*(1+Ei)(1+Eg) + (1-Eg)(1+Ef) ],  R = rcp((1+Ef)(1+Ei)(1+Eg))
// h  = sig(go)*tanh(c') with c' clamped so rcp can't see inf.
static __device__ __forceinline__ float cell_update(float gi, float gf, float gg,
                                                    float go, float& c) {
    float Ei = fexp2(gi * -L2E);
    float Eg = fexp2(gg * (-2.0f * L2E));
    float Ef = fexp2(gf * -L2E);
    float p1 = (1.0f + Ei) * (1.0f + Eg);
    float fe = 1.0f + Ef;
    float R  = frcp(fe * p1);
    c = R * (c * p1 + (1.0f - Eg) * fe);
    float cl = fminf(fmaxf(c, -18.0f), 18.0f);
    float Eo = fexp2(go * -L2E);
    float Ec = fexp2(cl * (-2.0f * L2E));
    float Ro = frcp((1.0f + Eo) * (1.0f + Ec));
    return (1.0f - Ec) * Ro;
}

#define MFMA(a, b, c) __builtin_amdgcn_mfma_f32_16x16x32_f16((a), (b), (c), 0, 0, 0)

__global__ __launch_bounds__(NTHR, 4) void lstm_mfma(
    const float* __restrict__ x,
    const float* __restrict__ W_ih0, const float* __restrict__ W_hh0,
    const float* __restrict__ b_ih0, const float* __restrict__ b_hh0,
    const float* __restrict__ W_ih1, const float* __restrict__ W_hh1,
    const float* __restrict__ b_ih1, const float* __restrict__ b_hh1,
    const float* __restrict__ W_fc,  const float* __restrict__ b_fc,
    float* __restrict__ out)
{
    __shared__ __align__(16) _Float16 Hf[2][2048];   // [buf][(ks*64+lane)*8+j]
    __shared__ float xs[TT * BT];

    const int tid = threadIdx.x;
    const int ln  = tid & 63;
    const int wv  = tid >> 6;         // wave 0..12 == tile index (both layers)
    const int m   = ln & 15;          // batch col
    const int q   = ln >> 4;          // quad
    const int b0g = blockIdx.x * BT;

    // ---------------- one-time init ----------------
    for (int i = tid; i < BT * TT; i += NTHR) {
        int b = i & 15, t = i >> 4;
        xs[t * BT + b] = x[(size_t)(b0g + b) * TT + t];
    }
    for (int i = tid; i < 2 * 2048; i += NTHR) ((_Float16*)Hf)[i] = (_Float16)0.f;

    // ---- A-fragments (gate-permuted rows), single f16 (RN cast) ----
    const int  uA   = 4 * wv + (m >> 2);
    const int  gA   = m & 3;
    const bool rokA = (uA < HH);
    const int  wrow = gA * HH + uA;

    half8 a0[2];                      // layer-0 (W_hh0), ks 0..1
    half8 a1[4];                      // layer-1 ([W_ih1|pad|W_hh1|pad]), ks 0..3
#pragma unroll
    for (int ks = 0; ks < 2; ++ks) {
        half8 h8;
#pragma unroll
        for (int j = 0; j < 8; ++j) {
            int k = ks * 32 + q * 8 + j;
            float w = (rokA && k < HH) ? W_hh0[wrow * HH + k] : 0.f;
            h8[j] = (_Float16)w;
        }
        a0[ks] = h8;
    }
#pragma unroll
    for (int ks = 0; ks < 4; ++ks) {
        half8 h8;
#pragma unroll
        for (int j = 0; j < 8; ++j) {
            int k = ks * 32 + q * 8 + j;
            float w = 0.f;
            if (rokA) {
                if (k < HH)                      w = W_ih1[wrow * HH + k];
                else if (k >= 64 && k < 64 + HH) w = W_hh1[wrow * HH + (k - 64)];
            }
            h8[j] = (_Float16)w;
        }
        a1[ks] = h8;
    }

    // ---- C-lane constants: unit uC = 4*wv + q, batch m, gate g = reg ----
    const int  uC = 4 * wv + q;       // 50,51 (wave 12, q>=2): dummies -> zero-wt K slots
    const bool vC = (uC < HH);
    float cc0[4], bw0[4], cc1[4];
#pragma unroll
    for (int g = 0; g < 4; ++g) {
        int rg = g * HH + (vC ? uC : 0);
        cc0[g] = vC ? (b_ih0[rg] + b_hh0[rg]) : 0.f;
        bw0[g] = vC ? W_ih0[rg] : 0.f;
        cc1[g] = vC ? (b_ih1[rg] + b_hh1[rg]) : 0.f;
    }
    const int kh = uC & 63;           // dummy units 50/51 land in zero-weight K slots
    const int widx = ((kh >> 5) * 64 + ((kh >> 3) & 3) * 16 + m) * 8 + (kh & 7);
    float c1 = 0.f, c2 = 0.f;

    __syncthreads();

    // one iteration: snapshot buf P (compile-time), L0(t=ttv) if DO_L0,
    // L1(t=ttv-1), write h -> buf P^1, barrier.
#define ITER(ttv, P, DO_L0)                                               \
    {                                                                     \
        half8 b0 = *(const half8*)&Hf[(P)][(0 * 64 + ln) * 8];            \
        half8 b1 = *(const half8*)&Hf[(P)][(1 * 64 + ln) * 8];            \
        half8 b2 = *(const half8*)&Hf[(P)][(2 * 64 + ln) * 8];            \
        half8 b3 = *(const half8*)&Hf[(P)][(3 * 64 + ln) * 8];            \
        if (DO_L0) {                                                      \
            const float xv = xs[(ttv) * BT + m];                          \
            floatx4 acc;                                                  \
            _Pragma("unroll")                                             \
            for (int g = 0; g < 4; ++g) acc[g] = cc0[g] + bw0[g] * xv;    \
            acc = MFMA(a0[0], b0, acc);                                   \
            acc = MFMA(a0[1], b1, acc);                                   \
            float h = cell_update(acc[0], acc[1], acc[2], acc[3], c1);    \
            Hf[(P) ^ 1][widx] = (_Float16)h;                              \
        }                                                                 \
        {                                                                 \
            floatx4 acc;                                                  \
            _Pragma("unroll")                                             \
            for (int g = 0; g < 4; ++g) acc[g] = cc1[g];                  \
            acc = MFMA(a1[0], b0, acc);                                   \
            acc = MFMA(a1[1], b1, acc);                                   \
            acc = MFMA(a1[2], b2, acc);                                   \
            acc = MFMA(a1[3], b3, acc);                                   \
            float h = cell_update(acc[0], acc[1], acc[2], acc[3], c2);    \
            Hf[(P) ^ 1][widx + 1024] = (_Float16)h;                       \
        }                                                                 \
        __syncthreads();                                                  \
    }

    // ---- tt = 0 (p=0): h=0 -> L0 needs no MFMA; h2(-1)=0 already in buf 1 ----
    {
        const float xv = xs[m];
        float h = cell_update(cc0[0] + bw0[0] * xv, cc0[1] + bw0[1] * xv,
                              cc0[2] + bw0[2] * xv, cc0[3] + bw0[3] * xv, c1);
        Hf[1][widx] = (_Float16)h;
        __syncthreads();
    }

    // ---- steady state: pairs (2k-1 [p=1], 2k [p=0]) for k = 1..255 ----
    for (int k = 1; k <= 255; ++k) {
        ITER(2 * k - 1, 1, true);
        ITER(2 * k,     0, true);
    }
    // ---- tail: tt = 511 (p=1, both), tt = 512 (p=0, L1 only) ----
    ITER(511, 1, true);
    ITER(512, 0, false);

    // ---------------- FC epilogue: h2(511) in buf 1, slots k = 64+u ----------------
    if (tid < BT) {
        float a = b_fc[0];
        for (int u = 0; u < HH; ++u) {
            int k = 64 + u;
            int idx = ((k >> 5) * 64 + ((k >> 3) & 3) * 16 + tid) * 8 + (k & 7);
            a = fmaf((float)Hf[1][idx], W_fc[u], a);
        }
        out[b0g + tid] = a;
    }
#undef ITER
}

extern "C" void kernel_launch(void* const* d_in, const int* in_sizes, int n_in,
                              void* d_out, int out_size, void* d_ws, size_t ws_size,
                              hipStream_t stream) {
    const float* x     = (const float*)d_in[0];
    const float* W_ih0 = (const float*)d_in[1];
    const float* W_hh0 = (const float*)d_in[2];
    const float* b_ih0 = (const float*)d_in[3];
    const float* b_hh0 = (const float*)d_in[4];
    const float* W_ih1 = (const float*)d_in[5];
    const float* W_hh1 = (const float*)d_in[6];
    const float* b_ih1 = (const float*)d_in[7];
    const float* b_hh1 = (const float*)d_in[8];
    const float* W_fc  = (const float*)d_in[9];
    const float* b_fc  = (const float*)d_in[10];
    float* out = (float*)d_out;

    dim3 grid(4096 / BT);   // 256 blocks = 1/CU
    dim3 block(NTHR);       // 13 waves
    lstm_mfma<<<grid, block, 0, stream>>>(x, W_ih0, W_hh0, b_ih0, b_hh0,
                                          W_ih1, W_hh1, b_ih1, b_hh1,
                                          W_fc, b_fc, out);
}

// Round 14
// 408.679 us; speedup vs baseline: 1.3630x; 1.0789x over previous
//
#include <hip/hip_runtime.h>

// 2-layer LSTM (H=50, B=4096, T=512, D_in=1) + FC(50->1), fused MFMA, round 14.
//
// = round-13 (13 waves x 1 tile, BT=16, 1 block/CU, 1 barrier/iter, gate-
// permuted rows, single-f16 weight product, single-f16 h state, merged-rcp
// cell) + GATE PRE-SCALING: every gate is consumed only via exp2(s_g * gate),
// s = {-log2e, -log2e, -2log2e, -log2e} for {i,f,g,o}. Fold s_g into the
// A-fragments, biases and W_ih0 at build time -> gates exit the MFMA already
// scaled; cell_update loses 4 v_mul per update (8 per wave-iter). Precision
// equivalent: (s*w) rounded to f16 has the same rel err as w.
// B-frag layout (r2-r13-verified): k -> ks=k>>5, lane=((k>>3)&3)*16+n, j=k&7.

#define TT 512
#define HH 50
#define BT 16
#define NTHR 832   // 13 waves
#define L2E 1.44269504f

typedef _Float16 half8 __attribute__((ext_vector_type(8)));
typedef float floatx4 __attribute__((ext_vector_type(4)));

static __device__ __forceinline__ float fexp2(float x) { return __builtin_amdgcn_exp2f(x); }
static __device__ __forceinline__ float frcp(float x)  { return __builtin_amdgcn_rcpf(x); }

// PRE-SCALED cell update: inputs are already s_g*gate, i.e. Ei=exp2(gi') etc.
// c' = sig(f)*c + sig(i)*tanh(g) = R*[c*(1+Ei)(1+Eg) + (1-Eg)(1+Ef)],
// R = rcp((1+Ef)(1+Ei)(1+Eg)); h = sig(o)*tanh(c'), c clamped (NaN guard).
// 5 exp + 2 rcp + 1 mul (only cl needs an exp2-arg multiply).
static __device__ __forceinline__ float cell_update(float gi, float gf, float gg,
                                                    float go, float& c) {
    float Ei = fexp2(gi);
    float Eg = fexp2(gg);
    float Ef = fexp2(gf);
    float p1 = (1.0f + Ei) * (1.0f + Eg);
    float fe = 1.0f + Ef;
    float R  = frcp(fe * p1);
    c = R * (c * p1 + (1.0f - Eg) * fe);
    float cl = fminf(fmaxf(c, -18.0f), 18.0f);
    float Eo = fexp2(go);
    float Ec = fexp2(cl * (-2.0f * L2E));
    float Ro = frcp((1.0f + Eo) * (1.0f + Ec));
    return (1.0f - Ec) * Ro;
}

#define MFMA(a, b, c) __builtin_amdgcn_mfma_f32_16x16x32_f16((a), (b), (c), 0, 0, 0)

__global__ __launch_bounds__(NTHR, 4) void lstm_mfma(
    const float* __restrict__ x,
    const float* __restrict__ W_ih0, const float* __restrict__ W_hh0,
    const float* __restrict__ b_ih0, const float* __restrict__ b_hh0,
    const float* __restrict__ W_ih1, const float* __restrict__ W_hh1,
    const float* __restrict__ b_ih1, const float* __restrict__ b_hh1,
    const float* __restrict__ W_fc,  const float* __restrict__ b_fc,
    float* __restrict__ out)
{
    __shared__ __align__(16) _Float16 Hf[2][2048];   // [buf][(ks*64+lane)*8+j]
    __shared__ float xs[TT * BT];

    const int tid = threadIdx.x;
    const int ln  = tid & 63;
    const int wv  = tid >> 6;         // wave 0..12 == tile index (both layers)
    const int m   = ln & 15;          // batch col
    const int q   = ln >> 4;          // quad
    const int b0g = blockIdx.x * BT;

    // per-gate exp2 pre-scales: i,f,o -> -log2e ; g(cell) -> -2log2e
    const float GSC[4] = { -L2E, -L2E, -2.0f * L2E, -L2E };

    // ---------------- one-time init ----------------
    for (int i = tid; i < BT * TT; i += NTHR) {
        int b = i & 15, t = i >> 4;
        xs[t * BT + b] = x[(size_t)(b0g + b) * TT + t];
    }
    for (int i = tid; i < 2 * 2048; i += NTHR) ((_Float16*)Hf)[i] = (_Float16)0.f;

    // ---- A-fragments (gate-permuted rows), single f16, PRE-SCALED ----
    const int  uA   = 4 * wv + (m >> 2);
    const int  gA   = m & 3;
    const bool rokA = (uA < HH);
    const int  wrow = gA * HH + uA;
    const float sA  = GSC[gA];

    half8 a0[2];                      // layer-0 (W_hh0), ks 0..1
    half8 a1[4];                      // layer-1 ([W_ih1|pad|W_hh1|pad]), ks 0..3
#pragma unroll
    for (int ks = 0; ks < 2; ++ks) {
        half8 h8;
#pragma unroll
        for (int j = 0; j < 8; ++j) {
            int k = ks * 32 + q * 8 + j;
            float w = (rokA && k < HH) ? W_hh0[wrow * HH + k] : 0.f;
            h8[j] = (_Float16)(sA * w);
        }
        a0[ks] = h8;
    }
#pragma unroll
    for (int ks = 0; ks < 4; ++ks) {
        half8 h8;
#pragma unroll
        for (int j = 0; j < 8; ++j) {
            int k = ks * 32 + q * 8 + j;
            float w = 0.f;
            if (rokA) {
                if (k < HH)                      w = W_ih1[wrow * HH + k];
                else if (k >= 64 && k < 64 + HH) w = W_hh1[wrow * HH + (k - 64)];
            }
            h8[j] = (_Float16)(sA * w);
        }
        a1[ks] = h8;
    }

    // ---- C-lane constants (pre-scaled): unit uC = 4*wv + q, gate g = reg ----
    const int  uC = 4 * wv + q;       // 50,51 (wave 12, q>=2): dummies -> zero-wt K slots
    const bool vC = (uC < HH);
    float cc0[4], bw0[4], cc1[4];
#pragma unroll
    for (int g = 0; g < 4; ++g) {
        int rg = g * HH + (vC ? uC : 0);
        cc0[g] = vC ? GSC[g] * (b_ih0[rg] + b_hh0[rg]) : 0.f;
        bw0[g] = vC ? GSC[g] * W_ih0[rg] : 0.f;
        cc1[g] = vC ? GSC[g] * (b_ih1[rg] + b_hh1[rg]) : 0.f;
    }
    const int kh = uC & 63;           // dummy units 50/51 land in zero-weight K slots
    const int widx = ((kh >> 5) * 64 + ((kh >> 3) & 3) * 16 + m) * 8 + (kh & 7);
    float c1 = 0.f, c2 = 0.f;

    __syncthreads();

    // one iteration: snapshot buf P (compile-time), L0(t=ttv) if DO_L0,
    // L1(t=ttv-1), write h -> buf P^1, barrier.
#define ITER(ttv, P, DO_L0)                                               \
    {                                                                     \
        half8 b0 = *(const half8*)&Hf[(P)][(0 * 64 + ln) * 8];            \
        half8 b1 = *(const half8*)&Hf[(P)][(1 * 64 + ln) * 8];            \
        half8 b2 = *(const half8*)&Hf[(P)][(2 * 64 + ln) * 8];            \
        half8 b3 = *(const half8*)&Hf[(P)][(3 * 64 + ln) * 8];            \
        if (DO_L0) {                                                      \
            const float xv = xs[(ttv) * BT + m];                          \
            floatx4 acc;                                                  \
            _Pragma("unroll")                                             \
            for (int g = 0; g < 4; ++g) acc[g] = cc0[g] + bw0[g] * xv;    \
            acc = MFMA(a0[0], b0, acc);                                   \
            acc = MFMA(a0[1], b1, acc);                                   \
            float h = cell_update(acc[0], acc[1], acc[2], acc[3], c1);    \
            Hf[(P) ^ 1][widx] = (_Float16)h;                              \
        }                                                                 \
        {                                                                 \
            floatx4 acc;                                                  \
            _Pragma("unroll")                                             \
            for (int g = 0; g < 4; ++g) acc[g] = cc1[g];                  \
            acc = MFMA(a1[0], b0, acc);                                   \
            acc = MFMA(a1[1], b1, acc);                                   \
            acc = MFMA(a1[2], b2, acc);                                   \
            acc = MFMA(a1[3], b3, acc);                                   \
            float h = cell_update(acc[0], acc[1], acc[2], acc[3], c2);    \
            Hf[(P) ^ 1][widx + 1024] = (_Float16)h;                       \
        }                                                                 \
        __syncthreads();                                                  \
    }

    // ---- tt = 0 (p=0): h=0 -> L0 needs no MFMA; h2(-1)=0 already in buf 1 ----
    {
        const float xv = xs[m];
        float h = cell_update(cc0[0] + bw0[0] * xv, cc0[1] + bw0[1] * xv,
                              cc0[2] + bw0[2] * xv, cc0[3] + bw0[3] * xv, c1);
        Hf[1][widx] = (_Float16)h;
        __syncthreads();
    }

    // ---- steady state: pairs (2k-1 [p=1], 2k [p=0]) for k = 1..255 ----
    for (int k = 1; k <= 255; ++k) {
        ITER(2 * k - 1, 1, true);
        ITER(2 * k,     0, true);
    }
    // ---- tail: tt = 511 (p=1, both), tt = 512 (p=0, L1 only) ----
    ITER(511, 1, true);
    ITER(512, 0, false);

    // ---------------- FC epilogue: h2(511) in buf 1, slots k = 64+u ----------------
    if (tid < BT) {
        float a = b_fc[0];
        for (int u = 0; u < HH; ++u) {
            int k = 64 + u;
            int idx = ((k >> 5) * 64 + ((k >> 3) & 3) * 16 + tid) * 8 + (k & 7);
            a = fmaf((float)Hf[1][idx], W_fc[u], a);
        }
        out[b0g + tid] = a;
    }
#undef ITER
}

extern "C" void kernel_launch(void* const* d_in, const int* in_sizes, int n_in,
                              void* d_out, int out_size, void* d_ws, size_t ws_size,
                              hipStream_t stream) {
    const float* x     = (const float*)d_in[0];
    const float* W_ih0 = (const float*)d_in[1];
    const float* W_hh0 = (const float*)d_in[2];
    const float* b_ih0 = (const float*)d_in[3];
    const float* b_hh0 = (const float*)d_in[4];
    const float* W_ih1 = (const float*)d_in[5];
    const float* W_hh1 = (const float*)d_in[6];
    const float* b_ih1 = (const float*)d_in[7];
    const float* b_hh1 = (const float*)d_in[8];
    const float* W_fc  = (const float*)d_in[9];
    const float* b_fc  = (const float*)d_in[10];
    float* out = (float*)d_out;

    dim3 grid(4096 / BT);   // 256 blocks = 1/CU
    dim3 block(NTHR);       // 13 waves
    lstm_mfma<<<grid, block, 0, stream>>>(x, W_ih0, W_hh0, b_ih0, b_hh0,
                                          W_ih1, W_hh1, b_ih1, b_hh1,
                                          W_fc, b_fc, out);
}